// Round 4
// baseline (2835.420 us; speedup 1.0000x reference)
//
#include <hip/hip_runtime.h>

#define NN 50000
#define NE 800000
#define OUTC 176  // 11 * 16

typedef unsigned int uint32;

// ---------- bf16 helpers (manual, RNE) ----------
__device__ __forceinline__ uint32 f2bf_rne(float f) {
  union { float f; uint32 u; } v; v.f = f;
  uint32 u = v.u;
  return (u + 0x7FFFu + ((u >> 16) & 1u)) >> 16;
}
__device__ __forceinline__ uint32 packbf2(float a, float b) {
  return f2bf_rne(a) | (f2bf_rne(b) << 16);
}
__device__ __forceinline__ float blo(uint32 u) {
  union { uint32 x; float f; } t; t.x = u << 16; return t.f;
}
__device__ __forceinline__ float bhi(uint32 u) {
  union { uint32 x; float f; } t; t.x = u & 0xFFFF0000u; return t.f;
}
__device__ __forceinline__ float bf2f(unsigned short v) {
  union { uint32 x; float f; } t; t.x = ((uint32)v) << 16; return t.f;
}
// signed byte b (0..3) of packed word -> float
__device__ __forceinline__ float sb2f(uint32 w, int b) {
  return (float)((int)(w << (24 - 8 * b)) >> 24);
}

// ---------- small kernels ----------
__global__ __launch_bounds__(256) void deg_count_kernel(const int* __restrict__ edst,
                                                        float* __restrict__ deg) {
  int e = blockIdx.x * 256 + threadIdx.x;
  if (e < NE) atomicAdd(&deg[edst[e]], 1.0f);
}

__global__ __launch_bounds__(256) void deg_inv_kernel(float* __restrict__ deg) {
  int n = blockIdx.x * 256 + threadIdx.x;
  if (n < NN) deg[n] = 1.0f / fmaxf(deg[n], 1.0f);
}

__global__ __launch_bounds__(256) void copy_col0_kernel(const float* __restrict__ hx,
                                                        float* __restrict__ out) {
  int n = blockIdx.x * 256 + threadIdx.x;
  if (n >= NN) return;
  const float4* s = reinterpret_cast<const float4*>(hx + (size_t)n * 16);
  float4* d = reinterpret_cast<float4*>(out + (size_t)n * OUTC);
  d[0] = s[0]; d[1] = s[1]; d[2] = s[2]; d[3] = s[3];
}

// ---------- filter-generating network ----------
// W[e,c,d] = w_flat[e, c*16+d]; stored d-major: row(e,d) = {W[e,c,d]}_c contiguous.
// Common layer-1 body: u = relu(ef @ w1 + b1).
__device__ __forceinline__ void fnet_layer1(const float* __restrict__ ef, long long e,
                                            const float* __restrict__ w1,
                                            const float* __restrict__ b1,
                                            float* u) {
  float f[13];
#pragma unroll
  for (int i = 0; i < 13; ++i) f[i] = ef[(size_t)e * 13 + i];
#pragma unroll
  for (int k = 0; k < 64; ++k) u[k] = b1[k];
#pragma unroll
  for (int i = 0; i < 13; ++i) {
    float fi = f[i];
#pragma unroll
    for (int k = 0; k < 64; ++k) u[k] = fmaf(fi, w1[i * 64 + k], u[k]);
  }
#pragma unroll
  for (int k = 0; k < 64; ++k) u[k] = fmaxf(u[k], 0.0f);
}

__global__ __launch_bounds__(256) void fnet_bf16_kernel(
    const float* __restrict__ ef, const float* __restrict__ w1, const float* __restrict__ b1,
    const float* __restrict__ w2, const float* __restrict__ b2,
    unsigned short* __restrict__ W, long long ebase, int ecnt) {
  int t = blockIdx.x * 256 + threadIdx.x;
  if (t >= ecnt) return;
  float u[64];
  fnet_layer1(ef, ebase + t, w1, b1, u);
  for (int d = 0; d < 16; ++d) {  // d uniform -> w2/b2 scalar loads
    float acc[16];
#pragma unroll
    for (int c = 0; c < 16; ++c) acc[c] = b2[c * 16 + d];
#pragma unroll 8
    for (int k = 0; k < 64; ++k) {
      float uk = u[k];
#pragma unroll
      for (int c = 0; c < 16; ++c) acc[c] = fmaf(uk, w2[k * 256 + c * 16 + d], acc[c]);
    }
    unsigned short* wrow = W + ((size_t)t << 8) + (d << 4);
    uint32 p[8];
#pragma unroll
    for (int q = 0; q < 8; ++q) p[q] = packbf2(acc[2 * q], acc[2 * q + 1]);
    uint4* dp = reinterpret_cast<uint4*>(wrow);
    dp[0] = make_uint4(p[0], p[1], p[2], p[3]);
    dp[1] = make_uint4(p[4], p[5], p[6], p[7]);
  }
}

// int8 with per-(e,d)-row bf16 scale: q = clamp(rint(W / s'), -127, 127), s' = bf16(rowmax/127).
__global__ __launch_bounds__(256) void fnet_i8_kernel(
    const float* __restrict__ ef, const float* __restrict__ w1, const float* __restrict__ b1,
    const float* __restrict__ w2, const float* __restrict__ b2,
    unsigned char* __restrict__ W, unsigned short* __restrict__ S) {
  int t = blockIdx.x * 256 + threadIdx.x;
  if (t >= NE) return;
  float u[64];
  fnet_layer1(ef, t, w1, b1, u);
  for (int d = 0; d < 16; ++d) {
    float acc[16];
#pragma unroll
    for (int c = 0; c < 16; ++c) acc[c] = b2[c * 16 + d];
#pragma unroll 8
    for (int k = 0; k < 64; ++k) {
      float uk = u[k];
#pragma unroll
      for (int c = 0; c < 16; ++c) acc[c] = fmaf(uk, w2[k * 256 + c * 16 + d], acc[c]);
    }
    float m = 0.0f;
#pragma unroll
    for (int c = 0; c < 16; ++c) m = fmaxf(m, fabsf(acc[c]));
    uint32 sbits = f2bf_rne(m * (1.0f / 127.0f));
    S[(size_t)t * 16 + d] = (unsigned short)sbits;
    float sdec = bf2f((unsigned short)sbits);
    float inv = (sdec > 0.0f) ? (1.0f / sdec) : 0.0f;
    uint32 p[4];
#pragma unroll
    for (int q = 0; q < 4; ++q) {
      uint32 w = 0;
#pragma unroll
      for (int b = 0; b < 4; ++b) {
        float qf = fminf(127.0f, fmaxf(-127.0f, rintf(acc[q * 4 + b] * inv)));
        w |= ((uint32)((int)qf & 255)) << (8 * b);
      }
      p[q] = w;
    }
    *reinterpret_cast<uint4*>(W + ((size_t)t << 8) + (d << 4)) =
        make_uint4(p[0], p[1], p[2], p[3]);
  }
}

// ---------- gconv message + aggregate ----------
// 16 lanes (d) per strip of 16 consecutive edges; sorted edge_dst -> register run
// accumulation, flush via atomicAdd on dst change.
__global__ __launch_bounds__(256) void msg_bf16_kernel(
    const float* __restrict__ h, int h_ld,
    const unsigned short* __restrict__ W, long long ebase, int ecnt,
    const int* __restrict__ idxn, const int* __restrict__ edst,
    float* __restrict__ agg) {
  int t = blockIdx.x * 256 + threadIdx.x;
  if (t >= ecnt) return;
  int g = t >> 4, d = t & 15;
  int cur = -1;
  float acc = 0.0f;
  for (int s = 0; s < 16; ++s) {
    int erel = g * 16 + s;
    long long e = ebase + erel;
    int dst = edst[e];
    if (dst != cur) {
      if (cur >= 0) atomicAdd(&agg[(size_t)cur * 16 + d], acc);
      cur = dst; acc = 0.0f;
    }
    int src = idxn[e];
    const float4* hp = reinterpret_cast<const float4*>(h + (size_t)src * h_ld);
    float4 a0 = hp[0], a1 = hp[1], a2 = hp[2], a3 = hp[3];
    const uint4* wp = reinterpret_cast<const uint4*>(W + ((size_t)erel << 8) + (d << 4));
    uint4 w0 = wp[0], w1 = wp[1];
    acc = fmaf(a0.x, blo(w0.x), acc); acc = fmaf(a0.y, bhi(w0.x), acc);
    acc = fmaf(a0.z, blo(w0.y), acc); acc = fmaf(a0.w, bhi(w0.y), acc);
    acc = fmaf(a1.x, blo(w0.z), acc); acc = fmaf(a1.y, bhi(w0.z), acc);
    acc = fmaf(a1.z, blo(w0.w), acc); acc = fmaf(a1.w, bhi(w0.w), acc);
    acc = fmaf(a2.x, blo(w1.x), acc); acc = fmaf(a2.y, bhi(w1.x), acc);
    acc = fmaf(a2.z, blo(w1.y), acc); acc = fmaf(a2.w, bhi(w1.y), acc);
    acc = fmaf(a3.x, blo(w1.z), acc); acc = fmaf(a3.y, bhi(w1.z), acc);
    acc = fmaf(a3.z, blo(w1.w), acc); acc = fmaf(a3.w, bhi(w1.w), acc);
  }
  if (cur >= 0) atomicAdd(&agg[(size_t)cur * 16 + d], acc);
}

__global__ __launch_bounds__(256) void msg_i8_kernel(
    const float* __restrict__ h, int h_ld,
    const unsigned char* __restrict__ W, const unsigned short* __restrict__ S,
    const int* __restrict__ idxn, const int* __restrict__ edst,
    float* __restrict__ agg) {
  int t = blockIdx.x * 256 + threadIdx.x;
  if (t >= NE) return;
  int g = t >> 4, d = t & 15;
  int cur = -1;
  float acc = 0.0f;
  for (int s = 0; s < 16; ++s) {
    int e = g * 16 + s;
    int dst = edst[e];
    if (dst != cur) {
      if (cur >= 0) atomicAdd(&agg[(size_t)cur * 16 + d], acc);
      cur = dst; acc = 0.0f;
    }
    int src = idxn[e];
    const float4* hp = reinterpret_cast<const float4*>(h + (size_t)src * h_ld);
    float4 a0 = hp[0], a1 = hp[1], a2 = hp[2], a3 = hp[3];
    uint4 wv = *reinterpret_cast<const uint4*>(W + ((size_t)e << 8) + (d << 4));
    float sc = bf2f(S[(size_t)e * 16 + d]);
    float r = 0.0f;
    r = fmaf(a0.x, sb2f(wv.x, 0), r); r = fmaf(a0.y, sb2f(wv.x, 1), r);
    r = fmaf(a0.z, sb2f(wv.x, 2), r); r = fmaf(a0.w, sb2f(wv.x, 3), r);
    r = fmaf(a1.x, sb2f(wv.y, 0), r); r = fmaf(a1.y, sb2f(wv.y, 1), r);
    r = fmaf(a1.z, sb2f(wv.y, 2), r); r = fmaf(a1.w, sb2f(wv.y, 3), r);
    r = fmaf(a2.x, sb2f(wv.z, 0), r); r = fmaf(a2.y, sb2f(wv.z, 1), r);
    r = fmaf(a2.z, sb2f(wv.z, 2), r); r = fmaf(a2.w, sb2f(wv.z, 3), r);
    r = fmaf(a3.x, sb2f(wv.w, 0), r); r = fmaf(a3.y, sb2f(wv.w, 1), r);
    r = fmaf(a3.z, sb2f(wv.w, 2), r); r = fmaf(a3.w, sb2f(wv.w, 3), r);
    acc = fmaf(r, sc, acc);
  }
  if (cur >= 0) atomicAdd(&agg[(size_t)cur * 16 + d], acc);
}

// ---------- fused degree-normalize + GRU cell + optional skip-add ----------
// hout/sprev may alias (col10 stash) -> no __restrict__, sprev read before hout write.
__global__ __launch_bounds__(256) void cell_kernel(
    const float* __restrict__ agg, const float* __restrict__ invd,
    const float* __restrict__ hin, int hin_ld,
    const float* __restrict__ wih, const float* __restrict__ whh,
    const float* __restrict__ bih, const float* __restrict__ bhh,
    float* hout, int hout_ld,
    const float* sprev, int sprev_ld,
    float* sout, int sout_ld) {
  int n = blockIdx.x * 256 + threadIdx.x;
  if (n >= NN) return;
  float x[16], h[16];
  float inv = invd[n];
  const float4* ap = reinterpret_cast<const float4*>(agg + (size_t)n * 16);
  const float4* hp = reinterpret_cast<const float4*>(hin + (size_t)n * hin_ld);
#pragma unroll
  for (int q = 0; q < 4; ++q) {
    float4 a = ap[q];
    x[4 * q + 0] = a.x * inv; x[4 * q + 1] = a.y * inv;
    x[4 * q + 2] = a.z * inv; x[4 * q + 3] = a.w * inv;
    float4 hv = hp[q];
    h[4 * q + 0] = hv.x; h[4 * q + 1] = hv.y; h[4 * q + 2] = hv.z; h[4 * q + 3] = hv.w;
  }
  float r[16], z[16], nn[16];
#pragma unroll
  for (int j = 0; j < 16; ++j) {
    float gi = bih[j], gh = bhh[j];
#pragma unroll
    for (int c = 0; c < 16; ++c) {
      gi = fmaf(x[c], wih[j * 16 + c], gi);
      gh = fmaf(h[c], whh[j * 16 + c], gh);
    }
    r[j] = 1.0f / (1.0f + expf(-(gi + gh)));
  }
#pragma unroll
  for (int j = 0; j < 16; ++j) {
    float gi = bih[16 + j], gh = bhh[16 + j];
#pragma unroll
    for (int c = 0; c < 16; ++c) {
      gi = fmaf(x[c], wih[(16 + j) * 16 + c], gi);
      gh = fmaf(h[c], whh[(16 + j) * 16 + c], gh);
    }
    z[j] = 1.0f / (1.0f + expf(-(gi + gh)));
  }
#pragma unroll
  for (int j = 0; j < 16; ++j) {
    float gi = bih[32 + j], gh = bhh[32 + j];
#pragma unroll
    for (int c = 0; c < 16; ++c) {
      gi = fmaf(x[c], wih[(32 + j) * 16 + c], gi);
      gh = fmaf(h[c], whh[(32 + j) * 16 + c], gh);
    }
    nn[j] = tanhf(gi + r[j] * gh);
  }
  float hv[16];
#pragma unroll
  for (int j = 0; j < 16; ++j) hv[j] = (1.0f - z[j]) * nn[j] + z[j] * h[j];

  float sv[16];
  bool do_s = (sprev != nullptr);
  if (do_s) {
    const float4* pp = reinterpret_cast<const float4*>(sprev + (size_t)n * sprev_ld);
#pragma unroll
    for (int q = 0; q < 4; ++q) {
      float4 p = pp[q];
      sv[4 * q + 0] = hv[4 * q + 0] + p.x; sv[4 * q + 1] = hv[4 * q + 1] + p.y;
      sv[4 * q + 2] = hv[4 * q + 2] + p.z; sv[4 * q + 3] = hv[4 * q + 3] + p.w;
    }
  }
  float4* hop = reinterpret_cast<float4*>(hout + (size_t)n * hout_ld);
#pragma unroll
  for (int q = 0; q < 4; ++q)
    hop[q] = make_float4(hv[4 * q], hv[4 * q + 1], hv[4 * q + 2], hv[4 * q + 3]);
  if (do_s) {
    float4* sp = reinterpret_cast<float4*>(sout + (size_t)n * sout_ld);
#pragma unroll
    for (int q = 0; q < 4; ++q)
      sp[q] = make_float4(sv[4 * q], sv[4 * q + 1], sv[4 * q + 2], sv[4 * q + 3]);
  }
}

extern "C" void kernel_launch(void* const* d_in, const int* in_sizes, int n_in,
                              void* d_out, int out_size, void* d_ws, size_t ws_size,
                              hipStream_t stream) {
  const float* hx   = (const float*)d_in[0];
  const float* ef   = (const float*)d_in[1];
  const int*   idxn = (const int*)d_in[2];
  const int*   edst = (const int*)d_in[3];
  const float* w1   = (const float*)d_in[4];
  const float* b1   = (const float*)d_in[5];
  const float* w2   = (const float*)d_in[6];
  const float* b2   = (const float*)d_in[7];
  const float* wih  = (const float*)d_in[8];
  const float* whh  = (const float*)d_in[9];
  const float* bih  = (const float*)d_in[10];
  const float* bhh  = (const float*)d_in[11];
  float* out = (float*)d_out;

  // workspace: invd [NN f32] | agg [NN*16 f32] | W (+ scales for int8 plan)
  const size_t INV_OFF = 0;
  const size_t AGG_OFF = 200064;              // NN*4 rounded up to 64
  const size_t W_OFF   = 3400192;             // AGG end rounded up to 256
  if (ws_size < W_OFF + 1600 * 512) return;
  char* wsb = (char*)d_ws;
  float* invd = (float*)(wsb + INV_OFF);
  float* agg  = (float*)(wsb + AGG_OFF);
  unsigned short* W16 = (unsigned short*)(wsb + W_OFF);
  unsigned char*  W8  = (unsigned char*)(wsb + W_OFF);
  unsigned short* S16 = (unsigned short*)(wsb + W_OFF + (size_t)NE * 256);
  size_t wrem = ws_size - W_OFF;

  int plan;       // 0 = full bf16, 1 = int8+row scale, 2 = chunked bf16
  size_t chunk = NE;
  if (wrem >= (size_t)NE * 512)      plan = 0;
  else if (wrem >= (size_t)NE * 288) plan = 1;
  else {
    plan = 2;
    chunk = (wrem / 512) & ~(size_t)15;
    if (chunk > NE) chunk = NE;
  }

  const int NB = (NN + 255) / 256;
  const int EB = (NE + 255) / 256;

  hipMemsetAsync(invd, 0, (size_t)NN * 4, stream);
  deg_count_kernel<<<EB, 256, 0, stream>>>(edst, invd);
  deg_inv_kernel<<<NB, 256, 0, stream>>>(invd);
  copy_col0_kernel<<<NB, 256, 0, stream>>>(hx, out);

  if (plan == 0)
    fnet_bf16_kernel<<<EB, 256, 0, stream>>>(ef, w1, b1, w2, b2, W16, 0, NE);
  else if (plan == 1)
    fnet_i8_kernel<<<EB, 256, 0, stream>>>(ef, w1, b1, w2, b2, W8, S16);

  auto col = [&](int c) { return out + (size_t)c * 16; };

  auto step = [&](const float* hin, int hin_ld, float* hout,
                  const float* sprev, float* sout) {
    hipMemsetAsync(agg, 0, (size_t)NN * 64, stream);
    if (plan == 0) {
      msg_bf16_kernel<<<EB, 256, 0, stream>>>(hin, hin_ld, W16, 0, NE, idxn, edst, agg);
    } else if (plan == 1) {
      msg_i8_kernel<<<EB, 256, 0, stream>>>(hin, hin_ld, W8, S16, idxn, edst, agg);
    } else {
      for (size_t e0 = 0; e0 < NE; e0 += chunk) {
        int cnt = (int)(((size_t)NE - e0) < chunk ? ((size_t)NE - e0) : chunk);
        fnet_bf16_kernel<<<(cnt + 255) / 256, 256, 0, stream>>>(ef, w1, b1, w2, b2, W16,
                                                                (long long)e0, cnt);
        msg_bf16_kernel<<<(cnt + 255) / 256, 256, 0, stream>>>(hin, hin_ld, W16,
                                                               (long long)e0, cnt,
                                                               idxn, edst, agg);
      }
    }
    cell_kernel<<<NB, 256, 0, stream>>>(agg, invd, hin, hin_ld, wih, whh, bih, bhh,
                                        hout, OUTC, sprev, OUTC, sout, OUTC);
  };

  // cols 0..10 = [hx,h1,h2,s1,h4,s2,h6,s3,h8,s4,h10]; col10 is the rotating stash
  // for h3/h5/h7/h9 (each overwritten after last use; h10 lands there finally).
  step(hx,      16,  col(1),  nullptr, nullptr);   // h1
  step(col(1), OUTC, col(2),  nullptr, nullptr);   // h2
  step(col(2), OUTC, col(10), col(1),  col(3));    // h3 -> stash, s1 = h1 + h3
  step(col(3), OUTC, col(4),  nullptr, nullptr);   // h4
  step(col(4), OUTC, col(10), col(10), col(5));    // h5 -> stash, s2 = h3 + h5
  step(col(5), OUTC, col(6),  nullptr, nullptr);   // h6
  step(col(6), OUTC, col(10), col(10), col(7));    // h7 -> stash, s3 = h5 + h7
  step(col(7), OUTC, col(8),  nullptr, nullptr);   // h8
  step(col(8), OUTC, col(10), col(10), col(9));    // h9 -> stash, s4 = h7 + h9
  step(col(9), OUTC, col(10), nullptr, nullptr);   // h10 (final, overwrites stash)
}